// Round 10
// baseline (138.787 us; speedup 1.0000x reference)
//
#include <hip/hip_runtime.h>
#include <hip/hip_bf16.h>

// Chamfer distance: B=8, N=M=4096, D=128, fp32 inputs, scalar fp32 out.
// dist[b,n,m] = ||p1||^2 + ||p2||^2 - 2*p1.p2
// bf1 holds (-2*p1) in bf16, so MFMA acc = -2*cross directly.
// Mins via biased-float-as-uint atomicMin (bias 16384 -> all keys positive;
// uint order == float order for positive floats).

#define BATCH 8
#define NPTS 4096
#define DIM 128
#define FBIAS 16384.0f

using bf16x8 = __attribute__((ext_vector_type(8))) short;
using f32x16 = __attribute__((ext_vector_type(16))) float;

// ------------- K1: fp32 -> bf16 (p1 scaled by -2) + exact fp32 norms --------
__global__ void prep_kernel(const float* __restrict__ p1,
                            const float* __restrict__ p2,
                            __hip_bfloat16* __restrict__ b1,
                            __hip_bfloat16* __restrict__ b2,
                            float* __restrict__ s1,
                            float* __restrict__ s2) {
    const int arr = blockIdx.y;
    const float* src = arr ? p2 : p1;
    __hip_bfloat16* dst = arr ? b2 : b1;
    float* sq = arr ? s2 : s1;
    const float scale = arr ? 1.0f : -2.0f;

    const int wid = threadIdx.x >> 6;
    const int l   = threadIdx.x & 63;
    const int p   = blockIdx.x * 4 + wid;   // one wave per point
    const float2 v = *reinterpret_cast<const float2*>(src + (size_t)p * DIM + l * 2);
    float s = v.x * v.x + v.y * v.y;        // norm from ORIGINAL values
    __hip_bfloat162 h = __float22bfloat162_rn(make_float2(v.x * scale, v.y * scale));
    *reinterpret_cast<__hip_bfloat162*>(dst + (size_t)p * DIM + l * 2) = h;
    #pragma unroll
    for (int off = 1; off < 64; off <<= 1) s += __shfl_xor(s, off);
    if (l == 0) sq[p] = s;
}

// async global->LDS, 16B per lane; lds base must be wave-uniform.
__device__ __forceinline__ void stage16(const __hip_bfloat16* g, void* lds) {
    __builtin_amdgcn_global_load_lds(
        (const __attribute__((address_space(1))) void*)g,
        (__attribute__((address_space(3))) void*)lds, 16, 0, 0);
}

// ------------- K2: tiled GEMM + fused directional mins ----------------------
// 1-D grid of 1024 blocks; b = id&7 (XCD-aligned batch; FETCH ~8.4MB).
// Block: 128 rows x 1024 cols as 16 m-tiles of 64 cols. Wave: 32 rows.
//
// R9 -> R10, two mechanisms:
// (1) 32x32x16 MFMA: 16 instr/tile/wave (was 32), better FLOP/cy, half the
//     acc-init and addressing VALU. C/D: col=l&31, row=(reg&3)+8*(reg>>2)
//     +4*(l>>5); A: row=l&31,k=(l>>5)*8+j; B: col=l&31,k=(l>>5)*8+j.
// (2) counted-vmcnt pipeline: raw s_barrier A (WAR fence: prev tile's
//     readers done before DMA overwrites), STAGE(next), deferred TAIL,
//     then "s_waitcnt vmcnt(4); s_barrier" (B: current tile's 4 loads --
//     issued LAST iteration -- have landed; the 4 just-issued stay in
//     flight). No vmem ops issue between STAGE and the vmcnt, so the
//     count is exact. Never vmcnt(0) in the loop.
// LDS swizzle widened to (row&15)<<4 (32 rows/read now); staging source
// permutation matches (chunk q ^ (row&15)).
//
// OCCUPANCY: 2nd __launch_bounds__ arg pins waves/EU; (256,4) = 128 unified
// regs/wave. Body ~114 regs. FETCH_SIZE is the spill canary (R3: 239MB).
__global__ void __launch_bounds__(256, 4)
chamfer_tile_kernel(const __hip_bfloat16* __restrict__ bf1,
                    const __hip_bfloat16* __restrict__ bf2,
                    const float* __restrict__ sq1,
                    const float* __restrict__ sq2,
                    unsigned int* __restrict__ min1u,   // [B][NPTS] biased keys
                    unsigned int* __restrict__ min2u) { // [B][NPTS] biased keys
    const int lin = blockIdx.x;
    const int b   = lin & 7;          // XCD-aligned batch
    const int rest = lin >> 3;
    const int nt  = rest & 31;        // n-tile (128 rows)
    const int mh  = rest >> 5;        // m quarter (1024 cols)
    const int tid = threadIdx.x;
    const int wid = tid >> 6;
    const int l   = tid & 63;
    const int l31 = l & 31;
    const int lh  = l >> 5;           // 0/1
    const int base = mh * 1024;

    __shared__ __align__(16) unsigned char btile[2][64 * 256]; // 2 x 16KB
    __shared__ unsigned int colminu[1024];                     // 4KB col-min acc

    const __hip_bfloat16* bf1b = bf1 + (size_t)b * NPTS * DIM;
    const __hip_bfloat16* bf2b = bf2 + (size_t)b * NPTS * DIM;
    const float* sq1b = sq1 + b * NPTS;
    const float* sq2b = sq2 + b * NPTS;

    const int n0 = nt * 128 + wid * 32;  // wave's first row

    // A fragments (32x32x16): row n0 + l31, k = ks*16 + lh*8
    bf16x8 afrag[8];
    #pragma unroll
    for (int ks = 0; ks < 8; ++ks)
        afrag[ks] = *reinterpret_cast<const bf16x8*>(
            bf1b + (n0 + l31) * DIM + ks * 16 + lh * 8);

    // sq1 for accumulator rows: n0 + (reg&3) + 8*(reg>>2) + 4*lh
    float sq1v[16];
    #pragma unroll
    for (int reg = 0; reg < 16; ++reg)
        sq1v[reg] = sq1b[n0 + (reg & 3) + 8 * (reg >> 2) + 4 * lh];

    float rmin[16];
    #pragma unroll
    for (int reg = 0; reg < 16; ++reg) rmin[reg] = 3.4e38f;

    // B-frag LDS read addressing (swizzle (row&15)<<4, separable):
    // addr(ks,ct) = bofs + ((ks*32) ^ vks) + ct*8192  [+ buffer base]
    const int bofs = l31 * 256 + ((lh * 16) ^ ((l & 1) << 4));
    const int vks  = (l & 14) << 4;

    // wave-level stage of 64-row B tile at column m0 into buffer `buf`.
    // linear LDS chunk (row,q) <- global chunk (q ^ (row&15)).
    auto STAGE = [&](int buf, int m0) {
        #pragma unroll
        for (int j = 0; j < 4; ++j) {
            const int c   = j * 256 + wid * 64 + l;   // [0, 1024)
            const int row = c >> 4;
            const int q   = c & 15;
            const __hip_bfloat16* src =
                bf2b + (size_t)(m0 + row) * DIM + (q ^ (row & 15)) * 8;
            stage16(src, &btile[buf][c * 16]);
        }
    };

    // deferred dir2 tail: fold lane halves (rows +0/+4), ds-min per column.
    auto TAIL = [&](float cp0, float cp1, int mtIdx) {
        float v0 = fminf(cp0, __shfl_xor(cp0, 32));
        float v1 = fminf(cp1, __shfl_xor(cp1, 32));
        if (l < 32) {
            atomicMin(&colminu[mtIdx * 64 + l], __float_as_uint(v0 + FBIAS));
            atomicMin(&colminu[mtIdx * 64 + 32 + l], __float_as_uint(v1 + FBIAS));
        }
    };

    // prologue: init col-min acc, stage tile 0
    #pragma unroll
    for (int i = 0; i < 4; ++i) colminu[i * 256 + tid] = 0xFFFFFFFFu;
    STAGE(0, base);

    float cp0 = 3.4e38f, cp1 = 3.4e38f;
    int cur = 0;

    for (int mt = 0; mt < 16; ++mt) {
        const int m0 = base + mt * 64;

        // A: all waves done READING btile[cur^1] (iter mt-1) -> safe to DMA.
        asm volatile("s_barrier" ::: "memory");
        if (mt < 15) STAGE(cur ^ 1, m0 + 64);
        if (mt > 0)  TAIL(cp0, cp1, mt - 1);
        // B: tile mt's 4 loads (issued last iter / prologue) landed in all
        // waves; the 4 just-issued stay in flight.
        if (mt < 15) asm volatile("s_waitcnt vmcnt(4)\n\ts_barrier" ::: "memory");
        else         asm volatile("s_waitcnt vmcnt(0)\n\ts_barrier" ::: "memory");

        // MFMA: 2 col-tiles of 32, K=128 in 8 steps
        f32x16 acc0 = {}, acc1 = {};
        const unsigned char* bt = &btile[cur][0];
        #pragma unroll
        for (int ks = 0; ks < 8; ++ks) {
            const int ko = ((ks * 32) ^ vks);
            bf16x8 b0 = *reinterpret_cast<const bf16x8*>(&bt[bofs + ko]);
            bf16x8 b1 = *reinterpret_cast<const bf16x8*>(&bt[bofs + ko + 8192]);
            acc0 = __builtin_amdgcn_mfma_f32_32x32x16_bf16(afrag[ks], b0, acc0, 0, 0, 0);
            acc1 = __builtin_amdgcn_mfma_f32_32x32x16_bf16(afrag[ks], b1, acc1, 0, 0, 0);
        }

        // dir1: row-mins. col(lane) = m0 + ct*32 + l31.
        const float s2v0 = sq2b[m0 + l31];
        const float s2v1 = sq2b[m0 + 32 + l31];
        #pragma unroll
        for (int reg = 0; reg < 16; ++reg)
            rmin[reg] = fminf(rmin[reg],
                              fminf(acc0[reg] + s2v0, acc1[reg] + s2v1)); // min3

        // dir2: col-mins over this wave's 16 reg-rows (per ct)
        float c0 = 3.4e38f, c1 = 3.4e38f;
        #pragma unroll
        for (int reg = 0; reg < 16; reg += 2) {
            c0 = fminf(c0, fminf(acc0[reg] + sq1v[reg],
                                 acc0[reg + 1] + sq1v[reg + 1]));  // min3
            c1 = fminf(c1, fminf(acc1[reg] + sq1v[reg],
                                 acc1[reg + 1] + sq1v[reg + 1]));  // min3
        }
        cp0 = c0; cp1 = c1;
        cur ^= 1;
    }

    // flush last tile's tail; then block-level combine
    TAIL(cp0, cp1, 15);
    __syncthreads();

    // dir2 finalize: one global atomicMin per column, once per block
    #pragma unroll
    for (int i = 0; i < 4; ++i) {
        const int c = i * 256 + tid;
        atomicMin(&min2u[(size_t)b * NPTS + base + c], colminu[c]);
    }

    // dir1 finalize: reduce each reg-row across the 32-lane group, then one
    // atomic per (row, lane-group). Lane group lh covers rows +4*lh.
    #pragma unroll
    for (int reg = 0; reg < 16; ++reg) {
        float v = rmin[reg];
        v = fminf(v, __shfl_xor(v, 1));
        v = fminf(v, __shfl_xor(v, 2));
        v = fminf(v, __shfl_xor(v, 4));
        v = fminf(v, __shfl_xor(v, 8));
        v = fminf(v, __shfl_xor(v, 16));
        rmin[reg] = v;
    }
    if (l31 == 0) {
        #pragma unroll
        for (int reg = 0; reg < 16; ++reg) {
            const int row = n0 + (reg & 3) + 8 * (reg >> 2) + 4 * lh;
            atomicMin(&min1u[(size_t)b * NPTS + row],
                      __float_as_uint(rmin[reg] + FBIAS));
        }
    }
}

// ------------- K3: combine, means, scalar out -------------------------------
// 256 blocks x 256 threads = 65536 = 2 * B * NPTS (exact, no guards)
__global__ void finalize_kernel(const unsigned int* __restrict__ min1u,
                                const unsigned int* __restrict__ min2u,
                                const float* __restrict__ sq1,
                                const float* __restrict__ sq2,
                                float* __restrict__ out) {
    const int tid = threadIdx.x;
    const int gid = blockIdx.x * 256 + tid;
    float sum;

    if (gid < BATCH * NPTS) {
        sum = (__uint_as_float(min1u[gid]) - FBIAS + sq1[gid])
              * (1.0f / (BATCH * NPTS));
    } else {
        const int idx = gid - BATCH * NPTS;
        sum = (__uint_as_float(min2u[idx]) - FBIAS + sq2[idx])
              * (1.0f / (BATCH * NPTS));
    }

    #pragma unroll
    for (int off = 1; off < 64; off <<= 1) sum += __shfl_xor(sum, off);
    __shared__ float wsum[4];
    if ((tid & 63) == 0) wsum[tid >> 6] = sum;
    __syncthreads();
    if (tid == 0) atomicAdd(out, wsum[0] + wsum[1] + wsum[2] + wsum[3]);
}

extern "C" void kernel_launch(void* const* d_in, const int* in_sizes, int n_in,
                              void* d_out, int out_size, void* d_ws, size_t ws_size,
                              hipStream_t stream) {
    const float* p1 = (const float*)d_in[0];
    const float* p2 = (const float*)d_in[1];
    float* out = (float*)d_out;

    const size_t npts_tot = (size_t)BATCH * NPTS;
    __hip_bfloat16* bf1 = (__hip_bfloat16*)d_ws;
    __hip_bfloat16* bf2 = bf1 + npts_tot * DIM;
    float* sq1 = (float*)(bf2 + npts_tot * DIM);
    float* sq2 = sq1 + npts_tot;
    unsigned int* min1u = (unsigned int*)(sq2 + npts_tot);  // [B][NPTS]
    unsigned int* min2u = min1u + npts_tot;                 // [B][NPTS]

    hipMemsetAsync(d_out, 0, sizeof(float), stream);
    hipMemsetAsync(min1u, 0xFF, npts_tot * 2 * sizeof(unsigned int), stream);

    prep_kernel<<<dim3(npts_tot / 4, 2), 256, 0, stream>>>(p1, p2, bf1, bf2, sq1, sq2);

    chamfer_tile_kernel<<<1024, 256, 0, stream>>>(bf1, bf2, sq1, sq2, min1u, min2u);

    finalize_kernel<<<256, 256, 0, stream>>>(min1u, min2u, sq1, sq2, out);
}

// Round 11
// 124.585 us; speedup vs baseline: 1.1140x; 1.1140x over previous
//
#include <hip/hip_runtime.h>
#include <hip/hip_bf16.h>

// Chamfer distance: B=8, N=M=4096, D=128, fp32 inputs, scalar fp32 out.
// K-EXTENDED GEMM (K=144): bf1e[n]=[-2*p1, sq1_hi, sq1_lo, 1, 1, 0*12],
// bf2e[m]=[p2, 1, 1, sq2_hi, sq2_lo, 0*12]  =>  MFMA acc = FULL squared
// distance (norms fused into the matmul; hi/lo bf16 split => ~2e-3 error).
// Row stride 288B = 18 chunks of 16B: naturally 2-way-bank-conflict-free
// (288B == 8 dwords mod 32 banks) -> NO LDS swizzle needed, and each
// 64-row tile is one contiguous 18KB block -> STAGE is a linear copy.
// Mins via biased-float-as-uint atomicMin (bias 16384 -> keys positive).

#define BATCH 8
#define NPTS 4096
#define DIM 128
#define DIME 144
#define ROWB 288          // bytes per extended row
#define FBIAS 16384.0f

using bf16x8 = __attribute__((ext_vector_type(8))) short;
using f32x16 = __attribute__((ext_vector_type(16))) float;

// ------------- K1: fp32 -> extended bf16 rows + min-buffer init -------------
__global__ void prep_kernel(const float* __restrict__ p1,
                            const float* __restrict__ p2,
                            __hip_bfloat16* __restrict__ b1,
                            __hip_bfloat16* __restrict__ b2,
                            unsigned int* __restrict__ minAll, // min1u||min2u
                            float* __restrict__ out) {
    const int arr = blockIdx.y;
    const float* src = arr ? p2 : p1;
    __hip_bfloat16* dst = arr ? b2 : b1;
    const float scale = arr ? 1.0f : -2.0f;

    const int wid = threadIdx.x >> 6;
    const int l   = threadIdx.x & 63;
    const int p   = blockIdx.x * 4 + wid;   // one wave per point

    const float2 v = *reinterpret_cast<const float2*>(src + (size_t)p * DIM + l * 2);
    float s = v.x * v.x + v.y * v.y;        // norm from ORIGINAL values
    __hip_bfloat162 h = __float22bfloat162_rn(make_float2(v.x * scale, v.y * scale));
    *reinterpret_cast<__hip_bfloat162*>(dst + (size_t)p * DIME + l * 2) = h;
    #pragma unroll
    for (int off = 1; off < 64; off <<= 1) s += __shfl_xor(s, off);

    // slots 128..143 written by lanes 0..7 (2 bf16 each)
    if (l < 8) {
        const __hip_bfloat16 shi = __float2bfloat16(s);
        const __hip_bfloat16 slo = __float2bfloat16(s - __bfloat162float(shi));
        const __hip_bfloat16 one = __float2bfloat16(1.0f);
        const __hip_bfloat16 zero = __float2bfloat16(0.0f);
        __hip_bfloat16 a = zero, bb = zero;
        if (arr == 0) {          // bf1e: [sq1_hi, sq1_lo, 1, 1, 0...]
            if (l == 0) { a = shi; bb = slo; }
            else if (l == 1) { a = one; bb = one; }
        } else {                 // bf2e: [1, 1, sq2_hi, sq2_lo, 0...]
            if (l == 0) { a = one; bb = one; }
            else if (l == 1) { a = shi; bb = slo; }
        }
        __hip_bfloat162 pair; pair.x = a; pair.y = bb;
        *reinterpret_cast<__hip_bfloat162*>(dst + (size_t)p * DIME + DIM + l * 2) = pair;
    }

    // fused init: min buffers (65536 uints over 8192 x-blocks) + out scalar
    if (arr == 0) {
        if (threadIdx.x < 8)
            minAll[blockIdx.x * 8 + threadIdx.x] = 0xFFFFFFFFu;
        if (blockIdx.x == 0 && threadIdx.x == 0) out[0] = 0.0f;
    }
}

// async global->LDS, 16B per lane; lds base must be wave-uniform.
__device__ __forceinline__ void stage16(const void* g, void* lds) {
    __builtin_amdgcn_global_load_lds(
        (const __attribute__((address_space(1))) void*)g,
        (__attribute__((address_space(3))) void*)lds, 16, 0, 0);
}

// ------------- K2: tiled GEMM (norms fused) + directional mins --------------
// 1-D grid of 1024 blocks; b = id&7 (XCD-aligned batch). Block: 128 rows x
// 1024 cols as 16 m-tiles of 64. Wave: 32 rows (one 32-row MFMA band).
// Counted-vmcnt pipeline: barrier A (WAR) -> STAGE(next,5 loads) -> TAIL
// (prev, ds-atomics only) -> s_waitcnt vmcnt(5); s_barrier (current tile
// landed; next tile's 5 stay in flight). Never vmcnt(0) in the loop.
// STAGE: tile is contiguous 18KB; 1280 lane-chunks cover 1152 (waves 2,3's
// 5th op re-copies chunks 0..127 with IDENTICAL data -> benign, keeps
// per-wave vmcnt uniform at 5).
// LDS: 2*18KB tiles + 4KB colminu = 40KB -> exactly 4 blocks/CU (160KiB).
// OCCUPANCY: 2nd launch_bounds arg pins waves/EU. Regs ~72 arch + 32 acc
// = 104 <= 128 @ (256,4). FETCH_SIZE is the spill canary (R10: sq1v[16]
// pushed it over -> 15.5/20MB; this round removes that state).
__global__ void __launch_bounds__(256, 4)
chamfer_tile_kernel(const __hip_bfloat16* __restrict__ bf1,
                    const __hip_bfloat16* __restrict__ bf2,
                    unsigned int* __restrict__ min1u,   // [B][NPTS] biased keys
                    unsigned int* __restrict__ min2u) { // [B][NPTS] biased keys
    const int lin = blockIdx.x;
    const int b   = lin & 7;          // XCD-aligned batch
    const int rest = lin >> 3;
    const int nt  = rest & 31;        // n-tile (128 rows)
    const int mh  = rest >> 5;        // m quarter (1024 cols)
    const int tid = threadIdx.x;
    const int wid = tid >> 6;
    const int l   = tid & 63;
    const int l31 = l & 31;
    const int lh  = l >> 5;           // 0/1
    const int base = mh * 1024;

    __shared__ __align__(16) unsigned char btile[2][64 * ROWB]; // 2 x 18KB
    __shared__ unsigned int colminu[1024];                      // 4KB

    const unsigned char* bf1b = (const unsigned char*)(bf1) + (size_t)b * NPTS * ROWB;
    const unsigned char* bf2b = (const unsigned char*)(bf2) + (size_t)b * NPTS * ROWB;

    const int n0 = nt * 128 + wid * 32;  // wave's first row

    // A fragments (32x32x16): row n0+l31, k = ks*16 + lh*8, ks=0..8
    bf16x8 afrag[9];
    #pragma unroll
    for (int ks = 0; ks < 9; ++ks)
        afrag[ks] = *reinterpret_cast<const bf16x8*>(
            bf1b + (size_t)(n0 + l31) * ROWB + ks * 32 + lh * 16);

    float rmin[16];
    #pragma unroll
    for (int reg = 0; reg < 16; ++reg) rmin[reg] = 3.4e38f;

    // B-frag read base: col row l31, k-offset lh*16; ct stride = 32*ROWB
    const int bofs = l31 * ROWB + lh * 16;

    // linear stage of the contiguous 18KB tile at column m0.
    auto STAGE = [&](int buf, int m0) {
        const unsigned char* tb = bf2b + (size_t)m0 * ROWB;
        #pragma unroll
        for (int j = 0; j < 5; ++j) {
            int c = j * 256 + tid;
            c = (c >= 1152) ? (c - 1152) : c;   // waves 2,3 j=4: re-copy chunks 0..127
            stage16(tb + c * 16, &btile[buf][c * 16]);
        }
    };

    // deferred dir2 tail: fold lane halves, ds-min per column.
    auto TAIL = [&](float cp0, float cp1, int mtIdx) {
        float v0 = fminf(cp0, __shfl_xor(cp0, 32));
        float v1 = fminf(cp1, __shfl_xor(cp1, 32));
        if (l < 32) {
            atomicMin(&colminu[mtIdx * 64 + l], __float_as_uint(v0 + FBIAS));
            atomicMin(&colminu[mtIdx * 64 + 32 + l], __float_as_uint(v1 + FBIAS));
        }
    };

    // prologue: init col-min acc, stage tile 0
    #pragma unroll
    for (int i = 0; i < 4; ++i) colminu[i * 256 + tid] = 0xFFFFFFFFu;
    STAGE(0, base);

    float cp0 = 3.4e38f, cp1 = 3.4e38f;
    int cur = 0;

    for (int mt = 0; mt < 16; ++mt) {
        const int m0 = base + mt * 64;

        // A: all waves done READING btile[cur^1] -> safe to overwrite via DMA.
        asm volatile("s_barrier" ::: "memory");
        if (mt < 15) STAGE(cur ^ 1, m0 + 64);
        if (mt > 0)  TAIL(cp0, cp1, mt - 1);
        // B: current tile's 5 loads landed; the 5 just-issued stay in flight.
        if (mt < 15) asm volatile("s_waitcnt vmcnt(5)\n\ts_barrier" ::: "memory");
        else         asm volatile("s_waitcnt vmcnt(0)\n\ts_barrier" ::: "memory");

        // MFMA: 2 col-tiles of 32, K=144 in 9 steps; acc = FULL distance
        f32x16 acc0 = {}, acc1 = {};
        const unsigned char* bt = &btile[cur][0];
        #pragma unroll
        for (int ks = 0; ks < 9; ++ks) {
            bf16x8 b0 = *reinterpret_cast<const bf16x8*>(&bt[bofs + ks * 32]);
            bf16x8 b1 = *reinterpret_cast<const bf16x8*>(&bt[bofs + ks * 32 + 32 * ROWB]);
            acc0 = __builtin_amdgcn_mfma_f32_32x32x16_bf16(afrag[ks], b0, acc0, 0, 0, 0);
            acc1 = __builtin_amdgcn_mfma_f32_32x32x16_bf16(afrag[ks], b1, acc1, 0, 0, 0);
        }

        // dir1: row-mins (one min3 per reg; acc is already the distance)
        #pragma unroll
        for (int reg = 0; reg < 16; ++reg)
            rmin[reg] = fminf(rmin[reg], fminf(acc0[reg], acc1[reg])); // v_min3

        // dir2: col-min trees over the 16 reg-rows, per ct
        float c0a = fminf(fminf(acc0[0], acc0[1]), fminf(acc0[2], acc0[3]));
        float c0b = fminf(fminf(acc0[4], acc0[5]), fminf(acc0[6], acc0[7]));
        float c0c = fminf(fminf(acc0[8], acc0[9]), fminf(acc0[10], acc0[11]));
        float c0d = fminf(fminf(acc0[12], acc0[13]), fminf(acc0[14], acc0[15]));
        cp0 = fminf(fminf(c0a, c0b), fminf(c0c, c0d));
        float c1a = fminf(fminf(acc1[0], acc1[1]), fminf(acc1[2], acc1[3]));
        float c1b = fminf(fminf(acc1[4], acc1[5]), fminf(acc1[6], acc1[7]));
        float c1c = fminf(fminf(acc1[8], acc1[9]), fminf(acc1[10], acc1[11]));
        float c1d = fminf(fminf(acc1[12], acc1[13]), fminf(acc1[14], acc1[15]));
        cp1 = fminf(fminf(c1a, c1b), fminf(c1c, c1d));

        cur ^= 1;
    }

    // flush last tile's tail; then block-level combine
    TAIL(cp0, cp1, 15);
    __syncthreads();

    // dir2 finalize: one global atomicMin per column, once per block
    #pragma unroll
    for (int i = 0; i < 4; ++i) {
        const int c = i * 256 + tid;
        atomicMin(&min2u[(size_t)b * NPTS + base + c], colminu[c]);
    }

    // dir1 finalize: reduce each reg-row across the 32-lane group, one
    // atomic per (row, lane-group). Row = n0 + (reg&3)+8*(reg>>2)+4*lh.
    #pragma unroll
    for (int reg = 0; reg < 16; ++reg) {
        float v = rmin[reg];
        v = fminf(v, __shfl_xor(v, 1));
        v = fminf(v, __shfl_xor(v, 2));
        v = fminf(v, __shfl_xor(v, 4));
        v = fminf(v, __shfl_xor(v, 8));
        v = fminf(v, __shfl_xor(v, 16));
        rmin[reg] = v;
    }
    if (l31 == 0) {
        #pragma unroll
        for (int reg = 0; reg < 16; ++reg) {
            const int row = n0 + (reg & 3) + 8 * (reg >> 2) + 4 * lh;
            atomicMin(&min1u[(size_t)b * NPTS + row],
                      __float_as_uint(rmin[reg] + FBIAS));
        }
    }
}

// ------------- K3: combine, means, scalar out -------------------------------
// 256 blocks x 256 threads = 65536 = 2 * B * NPTS. Keys are FULL distances.
__global__ void finalize_kernel(const unsigned int* __restrict__ minAll,
                                float* __restrict__ out) {
    const int tid = threadIdx.x;
    const int gid = blockIdx.x * 256 + tid;
    float sum = (__uint_as_float(minAll[gid]) - FBIAS)
                * (1.0f / (BATCH * NPTS));

    #pragma unroll
    for (int off = 1; off < 64; off <<= 1) sum += __shfl_xor(sum, off);
    __shared__ float wsum[4];
    if ((tid & 63) == 0) wsum[tid >> 6] = sum;
    __syncthreads();
    if (tid == 0) atomicAdd(out, wsum[0] + wsum[1] + wsum[2] + wsum[3]);
}

extern "C" void kernel_launch(void* const* d_in, const int* in_sizes, int n_in,
                              void* d_out, int out_size, void* d_ws, size_t ws_size,
                              hipStream_t stream) {
    const float* p1 = (const float*)d_in[0];
    const float* p2 = (const float*)d_in[1];
    float* out = (float*)d_out;

    const size_t npts_tot = (size_t)BATCH * NPTS;
    __hip_bfloat16* bf1e = (__hip_bfloat16*)d_ws;           // [32768][144]
    __hip_bfloat16* bf2e = bf1e + npts_tot * DIME;          // [32768][144]
    unsigned int* min1u = (unsigned int*)(bf2e + npts_tot * DIME); // [B][NPTS]
    unsigned int* min2u = min1u + npts_tot;                 // [B][NPTS]

    // 3 dispatches total (memsets + sq arrays fused away)
    prep_kernel<<<dim3(npts_tot / 4, 2), 256, 0, stream>>>(p1, p2, bf1e, bf2e,
                                                           min1u, out);
    chamfer_tile_kernel<<<1024, 256, 0, stream>>>(bf1e, bf2e, min1u, min2u);
    finalize_kernel<<<256, 256, 0, stream>>>(min1u, out);
}

// Round 12
// 123.952 us; speedup vs baseline: 1.1197x; 1.0051x over previous
//
#include <hip/hip_runtime.h>
#include <hip/hip_bf16.h>

// Chamfer distance: B=8, N=M=4096, D=128, fp32 inputs, scalar fp32 out.
// K-EXTENDED GEMM (K=144): bf1e[n]=[-2*p1, sq1_hi, sq1_lo, 1, 1, 0*12],
// bf2e[m]=[p2, 1, 1, sq2_hi, sq2_lo, 0*12]  =>  MFMA acc = FULL squared
// distance. Row = 288B = 18 x 16B chunks.
// R12: bit-4 XOR LDS swizzle (store chunk q at q ^ ((row>>2)&1); read banks
// 8*l31+4*((l31>>2)&1) -> each 8 lanes cover all 32 banks: conflict-free
// b128), STAGE addressing hoisted to prologue, zero-register MFMA init.
// Mins via biased-float-as-uint atomicMin (bias 16384 -> keys positive).

#define BATCH 8
#define NPTS 4096
#define DIM 128
#define DIME 144
#define ROWB 288          // bytes per extended row (global AND lds stride)
#define FBIAS 16384.0f

using bf16x8 = __attribute__((ext_vector_type(8))) short;
using f32x16 = __attribute__((ext_vector_type(16))) float;

// ------------- K1: fp32 -> extended bf16 rows + min-buffer init -------------
__global__ void prep_kernel(const float* __restrict__ p1,
                            const float* __restrict__ p2,
                            __hip_bfloat16* __restrict__ b1,
                            __hip_bfloat16* __restrict__ b2,
                            unsigned int* __restrict__ minAll, // min1u||min2u
                            float* __restrict__ out) {
    const int arr = blockIdx.y;
    const float* src = arr ? p2 : p1;
    __hip_bfloat16* dst = arr ? b2 : b1;
    const float scale = arr ? 1.0f : -2.0f;

    const int wid = threadIdx.x >> 6;
    const int l   = threadIdx.x & 63;
    const int p   = blockIdx.x * 4 + wid;   // one wave per point

    const float2 v = *reinterpret_cast<const float2*>(src + (size_t)p * DIM + l * 2);
    float s = v.x * v.x + v.y * v.y;        // norm from ORIGINAL values
    __hip_bfloat162 h = __float22bfloat162_rn(make_float2(v.x * scale, v.y * scale));
    *reinterpret_cast<__hip_bfloat162*>(dst + (size_t)p * DIME + l * 2) = h;
    #pragma unroll
    for (int off = 1; off < 64; off <<= 1) s += __shfl_xor(s, off);

    // slots 128..143 written by lanes 0..7 (2 bf16 each)
    if (l < 8) {
        const __hip_bfloat16 shi = __float2bfloat16(s);
        const __hip_bfloat16 slo = __float2bfloat16(s - __bfloat162float(shi));
        const __hip_bfloat16 one = __float2bfloat16(1.0f);
        const __hip_bfloat16 zero = __float2bfloat16(0.0f);
        __hip_bfloat16 a = zero, bb = zero;
        if (arr == 0) {          // bf1e: [sq1_hi, sq1_lo, 1, 1, 0...]
            if (l == 0) { a = shi; bb = slo; }
            else if (l == 1) { a = one; bb = one; }
        } else {                 // bf2e: [1, 1, sq2_hi, sq2_lo, 0...]
            if (l == 0) { a = one; bb = one; }
            else if (l == 1) { a = shi; bb = slo; }
        }
        __hip_bfloat162 pair; pair.x = a; pair.y = bb;
        *reinterpret_cast<__hip_bfloat162*>(dst + (size_t)p * DIME + DIM + l * 2) = pair;
    }

    // fused init: min buffers (65536 uints over 8192 x-blocks) + out scalar
    if (arr == 0) {
        if (threadIdx.x < 8)
            minAll[blockIdx.x * 8 + threadIdx.x] = 0xFFFFFFFFu;
        if (blockIdx.x == 0 && threadIdx.x == 0) out[0] = 0.0f;
    }
}

// async global->LDS, 16B per lane; lds base must be wave-uniform.
__device__ __forceinline__ void stage16(const void* g, void* lds) {
    __builtin_amdgcn_global_load_lds(
        (const __attribute__((address_space(1))) void*)g,
        (__attribute__((address_space(3))) void*)lds, 16, 0, 0);
}

// ------------- K2: tiled GEMM (norms fused) + directional mins --------------
// 1-D grid of 1024 blocks; b = id&7 (XCD-aligned batch). Block: 128 rows x
// 1024 cols as 16 m-tiles of 64. Wave: 32 rows (one 32-row MFMA band).
// Counted-vmcnt pipeline: barrier A (WAR) -> STAGE(next,5 loads) -> TAIL
// (prev, ds-atomics only) -> s_waitcnt vmcnt(5); s_barrier. Never vmcnt(0)
// in the loop.
// LDS SWIZZLE (R12): lds row chunk q holds global chunk q ^ ((row>>2)&1)
// (bijective pair-swap over all 18 chunks). ds_read bank-starts become
// 8*l31 + 4*((l31>>2)&1) mod 32 -> every 8 consecutive lanes hit all 32
// banks once -> conflict-free (R11: 288B linear had 4.7M conflicts = 2x).
// STAGE offsets (incl div-18) precomputed in prologue; MFMA first k-step
// consumes a live zero f32x16 (no per-tile acc-init movs).
// LDS: 2*18KB tiles + 4KB colminu = 40KB -> exactly 4 blocks/CU.
// OCCUPANCY: 2nd launch_bounds arg pins waves/EU; (256,4) budget 128 regs.
// Body ~122 (64+16 fz+10 stage +acc 32). FETCH_SIZE is the spill canary.
__global__ void __launch_bounds__(256, 4)
chamfer_tile_kernel(const __hip_bfloat16* __restrict__ bf1,
                    const __hip_bfloat16* __restrict__ bf2,
                    unsigned int* __restrict__ min1u,   // [B][NPTS] biased keys
                    unsigned int* __restrict__ min2u) { // [B][NPTS] biased keys
    const int lin = blockIdx.x;
    const int b   = lin & 7;          // XCD-aligned batch
    const int rest = lin >> 3;
    const int nt  = rest & 31;        // n-tile (128 rows)
    const int mh  = rest >> 5;        // m quarter (1024 cols)
    const int tid = threadIdx.x;
    const int wid = tid >> 6;
    const int l   = tid & 63;
    const int l31 = l & 31;
    const int lh  = l >> 5;           // 0/1
    const int base = mh * 1024;

    __shared__ __align__(16) unsigned char btile[2][64 * ROWB]; // 2 x 18KB
    __shared__ unsigned int colminu[1024];                      // 4KB

    const unsigned char* bf1b = (const unsigned char*)(bf1) + (size_t)b * NPTS * ROWB;
    const unsigned char* bf2b = (const unsigned char*)(bf2) + (size_t)b * NPTS * ROWB;

    const int n0 = nt * 128 + wid * 32;  // wave's first row

    // A fragments (32x32x16): row n0+l31, k = ks*16 + lh*8, ks=0..8 (global)
    bf16x8 afrag[9];
    #pragma unroll
    for (int ks = 0; ks < 9; ++ks)
        afrag[ks] = *reinterpret_cast<const bf16x8*>(
            bf1b + (size_t)(n0 + l31) * ROWB + ks * 32 + lh * 16);

    float rmin[16];
    #pragma unroll
    for (int reg = 0; reg < 16; ++reg) rmin[reg] = 3.4e38f;

    // B-frag LDS read base with bit-4 XOR unswizzle folded in:
    // logical o = ks*32 + lh*16 -> stored at o ^ (((l31>>2)&1)<<4).
    const int bofs = l31 * ROWB + ((lh ^ ((l31 >> 2) & 1)) << 4);

    // STAGE offsets, loop-invariant: LDS chunk c (linear dest) sources
    // global chunk row*18 + (q ^ ((row>>2)&1)). Wrap keeps vmcnt uniform 5.
    int srcOff[5], dstOff[5];
    #pragma unroll
    for (int j = 0; j < 5; ++j) {
        int c = j * 256 + tid;
        if (c >= 1152) c -= 1152;     // waves 2,3 j=4: benign re-copy
        const int row = c / 18, q = c - row * 18;
        srcOff[j] = row * ROWB + ((q ^ ((row >> 2) & 1)) << 4);
        dstOff[j] = c * 16;
    }
    auto STAGE = [&](int buf, int m0) {
        const unsigned char* tb = bf2b + (size_t)m0 * ROWB;
        #pragma unroll
        for (int j = 0; j < 5; ++j)
            stage16(tb + srcOff[j], &btile[buf][dstOff[j]]);
    };

    // deferred dir2 tail: fold lane halves, ds-min per column.
    auto TAIL = [&](float cp0, float cp1, int mtIdx) {
        float v0 = fminf(cp0, __shfl_xor(cp0, 32));
        float v1 = fminf(cp1, __shfl_xor(cp1, 32));
        if (l < 32) {
            atomicMin(&colminu[mtIdx * 64 + l], __float_as_uint(v0 + FBIAS));
            atomicMin(&colminu[mtIdx * 64 + 32 + l], __float_as_uint(v1 + FBIAS));
        }
    };

    // live zero accumulator source (kills 32 accvgpr-init movs per tile)
    const f32x16 fz = {};

    // prologue: init col-min acc, stage tile 0
    #pragma unroll
    for (int i = 0; i < 4; ++i) colminu[i * 256 + tid] = 0xFFFFFFFFu;
    STAGE(0, base);

    float cp0 = 3.4e38f, cp1 = 3.4e38f;
    int cur = 0;

    for (int mt = 0; mt < 16; ++mt) {
        const int m0 = base + mt * 64;

        // A: all waves done READING btile[cur^1] -> safe to overwrite via DMA.
        asm volatile("s_barrier" ::: "memory");
        if (mt < 15) STAGE(cur ^ 1, m0 + 64);
        if (mt > 0)  TAIL(cp0, cp1, mt - 1);
        // B: current tile's 5 loads landed; the 5 just-issued stay in flight.
        if (mt < 15) asm volatile("s_waitcnt vmcnt(5)\n\ts_barrier" ::: "memory");
        else         asm volatile("s_waitcnt vmcnt(0)\n\ts_barrier" ::: "memory");

        // MFMA: 2 col-tiles of 32, K=144 in 9 steps; acc = FULL distance
        const unsigned char* bt = &btile[cur][0];
        bf16x8 b0 = *reinterpret_cast<const bf16x8*>(&bt[bofs]);
        bf16x8 b1 = *reinterpret_cast<const bf16x8*>(&bt[bofs + 32 * ROWB]);
        f32x16 acc0 = __builtin_amdgcn_mfma_f32_32x32x16_bf16(afrag[0], b0, fz, 0, 0, 0);
        f32x16 acc1 = __builtin_amdgcn_mfma_f32_32x32x16_bf16(afrag[0], b1, fz, 0, 0, 0);
        #pragma unroll
        for (int ks = 1; ks < 9; ++ks) {
            b0 = *reinterpret_cast<const bf16x8*>(&bt[bofs + ks * 32]);
            b1 = *reinterpret_cast<const bf16x8*>(&bt[bofs + ks * 32 + 32 * ROWB]);
            acc0 = __builtin_amdgcn_mfma_f32_32x32x16_bf16(afrag[ks], b0, acc0, 0, 0, 0);
            acc1 = __builtin_amdgcn_mfma_f32_32x32x16_bf16(afrag[ks], b1, acc1, 0, 0, 0);
        }

        // dir1: row-mins (one min3 per reg; acc is already the distance)
        #pragma unroll
        for (int reg = 0; reg < 16; ++reg)
            rmin[reg] = fminf(rmin[reg], fminf(acc0[reg], acc1[reg])); // v_min3

        // dir2: col-min trees over the 16 reg-rows, per ct
        float c0a = fminf(fminf(acc0[0], acc0[1]), fminf(acc0[2], acc0[3]));
        float c0b = fminf(fminf(acc0[4], acc0[5]), fminf(acc0[6], acc0[7]));
        float c0c = fminf(fminf(acc0[8], acc0[9]), fminf(acc0[10], acc0[11]));
        float c0d = fminf(fminf(acc0[12], acc0[13]), fminf(acc0[14], acc0[15]));
        cp0 = fminf(fminf(c0a, c0b), fminf(c0c, c0d));
        float c1a = fminf(fminf(acc1[0], acc1[1]), fminf(acc1[2], acc1[3]));
        float c1b = fminf(fminf(acc1[4], acc1[5]), fminf(acc1[6], acc1[7]));
        float c1c = fminf(fminf(acc1[8], acc1[9]), fminf(acc1[10], acc1[11]));
        float c1d = fminf(fminf(acc1[12], acc1[13]), fminf(acc1[14], acc1[15]));
        cp1 = fminf(fminf(c1a, c1b), fminf(c1c, c1d));

        cur ^= 1;
    }

    // flush last tile's tail; then block-level combine
    TAIL(cp0, cp1, 15);
    __syncthreads();

    // dir2 finalize: one global atomicMin per column, once per block
    #pragma unroll
    for (int i = 0; i < 4; ++i) {
        const int c = i * 256 + tid;
        atomicMin(&min2u[(size_t)b * NPTS + base + c], colminu[c]);
    }

    // dir1 finalize: reduce each reg-row across the 32-lane group, one
    // atomic per (row, lane-group). Row = n0 + (reg&3)+8*(reg>>2)+4*lh.
    #pragma unroll
    for (int reg = 0; reg < 16; ++reg) {
        float v = rmin[reg];
        v = fminf(v, __shfl_xor(v, 1));
        v = fminf(v, __shfl_xor(v, 2));
        v = fminf(v, __shfl_xor(v, 4));
        v = fminf(v, __shfl_xor(v, 8));
        v = fminf(v, __shfl_xor(v, 16));
        rmin[reg] = v;
    }
    if (l31 == 0) {
        #pragma unroll
        for (int reg = 0; reg < 16; ++reg) {
            const int row = n0 + (reg & 3) + 8 * (reg >> 2) + 4 * lh;
            atomicMin(&min1u[(size_t)b * NPTS + row],
                      __float_as_uint(rmin[reg] + FBIAS));
        }
    }
}

// ------------- K3: combine, means, scalar out -------------------------------
// 256 blocks x 256 threads = 65536 = 2 * B * NPTS. Keys are FULL distances.
__global__ void finalize_kernel(const unsigned int* __restrict__ minAll,
                                float* __restrict__ out) {
    const int tid = threadIdx.x;
    const int gid = blockIdx.x * 256 + tid;
    float sum = (__uint_as_float(minAll[gid]) - FBIAS)
                * (1.0f / (BATCH * NPTS));

    #pragma unroll
    for (int off = 1; off < 64; off <<= 1) sum += __shfl_xor(sum, off);
    __shared__ float wsum[4];
    if ((tid & 63) == 0) wsum[tid >> 6] = sum;
    __syncthreads();
    if (tid == 0) atomicAdd(out, wsum[0] + wsum[1] + wsum[2] + wsum[3]);
}

extern "C" void kernel_launch(void* const* d_in, const int* in_sizes, int n_in,
                              void* d_out, int out_size, void* d_ws, size_t ws_size,
                              hipStream_t stream) {
    const float* p1 = (const float*)d_in[0];
    const float* p2 = (const float*)d_in[1];
    float* out = (float*)d_out;

    const size_t npts_tot = (size_t)BATCH * NPTS;
    __hip_bfloat16* bf1e = (__hip_bfloat16*)d_ws;           // [32768][144]
    __hip_bfloat16* bf2e = bf1e + npts_tot * DIME;          // [32768][144]
    unsigned int* min1u = (unsigned int*)(bf2e + npts_tot * DIME); // [B][NPTS]
    unsigned int* min2u = min1u + npts_tot;                 // [B][NPTS]

    // 3 dispatches total
    prep_kernel<<<dim3(npts_tot / 4, 2), 256, 0, stream>>>(p1, p2, bf1e, bf2e,
                                                           min1u, out);
    chamfer_tile_kernel<<<1024, 256, 0, stream>>>(bf1e, bf2e, min1u, min2u);
    finalize_kernel<<<256, 256, 0, stream>>>(min1u, out);
}